// Round 1
// baseline (10034.880 us; speedup 1.0000x reference)
//
#include <hip/hip_runtime.h>
#include <hip/hip_bf16.h>
#include <math.h>

#define TT 512
#define BB 128
#define DD 256
#define HH 512
#define EPSF 1e-7f

typedef unsigned int u32;

__device__ __forceinline__ float bf_lo(u32 u){ return __uint_as_float(u << 16); }
__device__ __forceinline__ float bf_hi(u32 u){ return __uint_as_float(u & 0xffff0000u); }

// ---------------------------------------------------------------------------
// Setup: concrete-dropout masks zx (4,B,D), zh (4,B,H), combined bias bx+bh,
// and bf16 copy of Wh (layout unchanged: [g][k][h]).
// ---------------------------------------------------------------------------
__global__ void setup_kernel(const float* __restrict__ ux, const float* __restrict__ uh,
                             const float* __restrict__ p_logit,
                             const float* __restrict__ bx, const float* __restrict__ bh,
                             const float* __restrict__ Wh,
                             float* __restrict__ zx, float* __restrict__ zh,
                             float* __restrict__ bias, __hip_bfloat16* __restrict__ whb){
  const int i = blockIdx.x*256 + threadIdx.x;
  const float p = 1.0f/(1.0f+expf(-p_logit[0]));
  const float lp = logf(p+EPSF) - logf(1.0f-p+EPSF);
  const float inv1mp = 1.0f/(1.0f-p);
  const int NZX = 4*BB*DD;      // 131072
  const int NZH = 4*BB*HH;      // 262144
  const int NB  = 4*HH;         // 2048
  const int NW  = 4*HH*HH;      // 1048576
  if (i < NZX){
    float u = ux[i];
    float l = (lp + logf(u+EPSF) - logf(1.0f-u+EPSF)) * 10.0f;  // /TEMP, TEMP=0.1
    zx[i] = (1.0f - 1.0f/(1.0f+expf(-l))) * inv1mp;
  } else if (i < NZX+NZH){
    int j = i - NZX;
    float u = uh[j];
    float l = (lp + logf(u+EPSF) - logf(1.0f-u+EPSF)) * 10.0f;
    zh[j] = (1.0f - 1.0f/(1.0f+expf(-l))) * inv1mp;
  } else if (i < NZX+NZH+NB){
    int j = i - NZX - NZH;
    bias[j] = bx[j] + bh[j];
  } else if (i < NZX+NZH+NB+NW){
    int j = i - NZX - NZH - NB;
    whb[j] = __float2bfloat16(Wh[j]);
  }
}

// ---------------------------------------------------------------------------
// Transpose Wx[g][h][d] -> WxT[g][d][h] (coalesced GEMM B-loads need d-major).
// ---------------------------------------------------------------------------
__global__ void transpose_wx(const float* __restrict__ Wx, float* __restrict__ WxT){
  __shared__ float tile[32][33];
  const int g = blockIdx.z, hb = blockIdx.y, db = blockIdx.x;
  const int tx = threadIdx.x, ty = threadIdx.y;
  for (int i = 0; i < 4; i++)
    tile[ty + i*8][tx] = Wx[((size_t)g*HH + hb*32 + ty + i*8)*DD + db*32 + tx];
  __syncthreads();
  for (int i = 0; i < 4; i++)
    WxT[((size_t)g*DD + db*32 + ty + i*8)*HH + hb*32 + tx] = tile[tx][ty + i*8];
}

// ---------------------------------------------------------------------------
// xproj GEMM (fp32 compute, bf16 out): per block one (g, b, 128t x 128h) tile,
// K=D=256 in chunks of 16.  Micro-tile 8x8 per thread (strided rows/cols so
// LDS reads are conflict-free / broadcast and C-writes stay coalesced).
// xp layout: [t][g][b][h] bf16.
// ---------------------------------------------------------------------------
__global__ __launch_bounds__(256)
void xproj_gemm(const float* __restrict__ input, const float* __restrict__ zx,
                const float* __restrict__ WxT, __hip_bfloat16* __restrict__ xp){
  __shared__ float As[128][17];
  __shared__ float Bs[16][129];
  const int bid = blockIdx.x;
  const int ht = bid & 3, tt = (bid>>2)&3, b = (bid>>4)&127, g = bid>>11;
  const int t0 = tt*128, h0 = ht*128;
  const int tid = threadIdx.x, tx = tid&15, ty = tid>>4;
  float acc[8][8];
  #pragma unroll
  for (int i=0;i<8;i++)
    #pragma unroll
    for (int j=0;j<8;j++) acc[i][j] = 0.0f;

  for (int d0 = 0; d0 < DD; d0 += 16){
    #pragma unroll
    for (int i = 0; i < 8; i++){
      int idx = tid + i*256;
      int row = idx >> 4, dl = idx & 15;
      As[row][dl] = input[((size_t)(t0+row)*BB + b)*DD + d0 + dl]
                  * zx[((size_t)g*BB + b)*DD + d0 + dl];
    }
    #pragma unroll
    for (int i = 0; i < 8; i++){
      int idx = tid + i*256;
      int dl = idx >> 7, hl = idx & 127;
      Bs[dl][hl] = WxT[((size_t)g*DD + d0 + dl)*HH + h0 + hl];
    }
    __syncthreads();
    #pragma unroll
    for (int dd = 0; dd < 16; dd++){
      float a[8], bb[8];
      #pragma unroll
      for (int i=0;i<8;i++) a[i] = As[ty + i*16][dd];
      #pragma unroll
      for (int j=0;j<8;j++) bb[j] = Bs[dd][tx + j*16];
      #pragma unroll
      for (int i=0;i<8;i++)
        #pragma unroll
        for (int j=0;j<8;j++) acc[i][j] += a[i]*bb[j];
    }
    __syncthreads();
  }
  #pragma unroll
  for (int i=0;i<8;i++){
    int t = t0 + ty + i*16;
    #pragma unroll
    for (int j=0;j<8;j++){
      int h = h0 + tx + j*16;
      xp[(((size_t)t*4 + g)*BB + b)*HH + h] = __float2bfloat16(acc[i][j]);
    }
  }
}

// ---------------------------------------------------------------------------
// One LSTM time step, fused gates GEMM + elementwise.
// Grid: 256 blocks = 32 kslices(16) x 8 bslices(16); 256 threads.
// Block stages Wh[4][k16][512] and hm[4][b16][512] (both bf16) into LDS,
// each thread computes gates for (g, b, 4 consecutive k), then all 4 gates
// of each (b,k) are combined via a small LDS exchange for the cell update.
// hm double-buffered across steps (kernel boundary = barrier).
// ---------------------------------------------------------------------------
__global__ __launch_bounds__(256, 1)
void lstm_step(const __hip_bfloat16* __restrict__ xp,
               const u32* __restrict__ whb,
               const float* __restrict__ zh,
               const float* __restrict__ bias,
               const u32* __restrict__ hmp,
               __hip_bfloat16* __restrict__ hmn,
               float* __restrict__ cbuf,
               float* __restrict__ hn,
               float* __restrict__ htc,
               int t){
  __shared__ u32 Wl[4][16][260];   // pad 260: bank stride 4 -> worst 2-way (free)
  __shared__ u32 Hl[4][16][260];
  __shared__ float gl[4][16][16];
  const int tid = threadIdx.x;
  const int kb = blockIdx.x & 31, bb = blockIdx.x >> 5;
  const int k0 = kb*16, b0 = bb*16;

  const uint4* w4 = (const uint4*)whb;
  #pragma unroll
  for (int i = 0; i < 16; i++){
    int idx = i*256 + tid;               // uint4 index 0..4095
    int hq = idx & 63, kl = (idx>>6)&15, g = idx>>10;
    uint4 v = w4[((size_t)g*HH + k0 + kl)*64 + hq];
    u32* dst = &Wl[g][kl][hq*4];
    dst[0]=v.x; dst[1]=v.y; dst[2]=v.z; dst[3]=v.w;
  }
  if (t == 0){
    #pragma unroll
    for (int i = 0; i < 16; i++){
      int idx = i*256 + tid;
      int hq = idx & 63, bl = (idx>>6)&15, g = idx>>10;
      u32* dst = &Hl[g][bl][hq*4];
      dst[0]=0u; dst[1]=0u; dst[2]=0u; dst[3]=0u;
    }
  } else {
    const uint4* h4 = (const uint4*)hmp;
    #pragma unroll
    for (int i = 0; i < 16; i++){
      int idx = i*256 + tid;
      int hq = idx & 63, bl = (idx>>6)&15, g = idx>>10;
      uint4 v = h4[((size_t)g*BB + b0 + bl)*64 + hq];
      u32* dst = &Hl[g][bl][hq*4];
      dst[0]=v.x; dst[1]=v.y; dst[2]=v.z; dst[3]=v.w;
    }
  }
  __syncthreads();

  const int g = tid >> 6, bl = (tid>>2)&15, kq = tid&3;
  const int b = b0 + bl;
  float acc0, acc1, acc2, acc3;
  {
    const float4 bv = *(const float4*)&bias[g*HH + k0 + kq*4];
    const uint2 xv = *(const uint2*)(xp + ((((size_t)t*4 + g)*BB + b)*HH + k0 + kq*4));
    acc0 = bv.x + bf_lo(xv.x); acc1 = bv.y + bf_hi(xv.x);
    acc2 = bv.z + bf_lo(xv.y); acc3 = bv.w + bf_hi(xv.y);
  }
  const u32* hr = &Hl[g][bl][0];
  const u32* w0 = &Wl[g][kq*4+0][0];
  const u32* w1 = &Wl[g][kq*4+1][0];
  const u32* w2 = &Wl[g][kq*4+2][0];
  const u32* w3 = &Wl[g][kq*4+3][0];
  for (int hw = 0; hw < 256; hw += 4){
    uint4 hv = *(const uint4*)(hr + hw);
    uint4 a0 = *(const uint4*)(w0 + hw);
    uint4 a1 = *(const uint4*)(w1 + hw);
    uint4 a2 = *(const uint4*)(w2 + hw);
    uint4 a3 = *(const uint4*)(w3 + hw);
    u32 hc, c0, c1, c2, c3;
    #pragma unroll
    for (int c = 0; c < 4; c++){
      hc = (c==0)?hv.x:(c==1)?hv.y:(c==2)?hv.z:hv.w;
      c0 = (c==0)?a0.x:(c==1)?a0.y:(c==2)?a0.z:a0.w;
      c1 = (c==0)?a1.x:(c==1)?a1.y:(c==2)?a1.z:a1.w;
      c2 = (c==0)?a2.x:(c==1)?a2.y:(c==2)?a2.z:a2.w;
      c3 = (c==0)?a3.x:(c==1)?a3.y:(c==2)?a3.z:a3.w;
      float hl = bf_lo(hc), hh = bf_hi(hc);
      acc0 += hl*bf_lo(c0) + hh*bf_hi(c0);
      acc1 += hl*bf_lo(c1) + hh*bf_hi(c1);
      acc2 += hl*bf_lo(c2) + hh*bf_hi(c2);
      acc3 += hl*bf_lo(c3) + hh*bf_hi(c3);
    }
  }
  gl[g][bl][kq*4+0] = acc0;
  gl[g][bl][kq*4+1] = acc1;
  gl[g][bl][kq*4+2] = acc2;
  gl[g][bl][kq*4+3] = acc3;
  __syncthreads();
  {
    const int bl2 = tid >> 4, kl2 = tid & 15;
    float gi = gl[0][bl2][kl2];
    float gf = gl[1][bl2][kl2];
    float go = gl[2][bl2][kl2];
    float gg = gl[3][bl2][kl2];
    float iv = 1.0f/(1.0f+__expf(-gi));
    float fv = 1.0f/(1.0f+__expf(-gf));
    float ov = 1.0f/(1.0f+__expf(-go));
    float gv = tanhf(gg);
    const int b2 = b0 + bl2, k2 = k0 + kl2;
    const size_t ci = (size_t)b2*HH + k2;
    float cp = (t==0) ? 0.0f : cbuf[ci];
    float cn = fv*cp + iv*gv;
    float hv2 = ov*tanhf(cn);
    cbuf[ci] = cn;
    hn[(size_t)t*BB*HH + ci] = hv2;
    #pragma unroll
    for (int gg2 = 0; gg2 < 4; gg2++){
      hmn[((size_t)gg2*BB + b2)*HH + k2] =
          __float2bfloat16(hv2 * zh[((size_t)gg2*BB + b2)*HH + k2]);
    }
    if (t == TT-1){
      htc[ci] = hv2;
      htc[(size_t)BB*HH + ci] = cn;
    }
  }
}

// ---------------------------------------------------------------------------
extern "C" void kernel_launch(void* const* d_in, const int* in_sizes, int n_in,
                              void* d_out, int out_size, void* d_ws, size_t ws_size,
                              hipStream_t stream){
  const float* input   = (const float*)d_in[0];
  const float* ux      = (const float*)d_in[1];
  const float* uh      = (const float*)d_in[2];
  const float* p_logit = (const float*)d_in[3];
  const float* Wx      = (const float*)d_in[4];
  const float* bx      = (const float*)d_in[5];
  const float* Wh      = (const float*)d_in[6];
  const float* bh      = (const float*)d_in[7];

  char* ws = (char*)d_ws;
  const size_t o_zx  = 0;                       // 4*B*D f32   = 524288 B
  const size_t o_zh  = o_zx  + 524288;          // 4*B*H f32   = 1048576 B
  const size_t o_b   = o_zh  + 1048576;         // 4*H   f32   = 8192 B
  const size_t o_wxt = o_b   + 8192;            // 4*D*H f32   = 2097152 B
  const size_t o_whb = o_wxt + 2097152;         // 4*H*H bf16  = 2097152 B
  const size_t o_c   = o_whb + 2097152;         // B*H   f32   = 262144 B
  const size_t o_h0  = o_c   + 262144;          // hm buf bf16 = 524288 B
  const size_t o_h1  = o_h0  + 524288;
  const size_t o_xp  = o_h1  + 524288;          // T*4*B*H bf16 = 268435456 B
  const size_t need  = o_xp + 268435456;
  if (ws_size < need) return;  // workspace too small -> fail loudly

  float* zx   = (float*)(ws + o_zx);
  float* zh   = (float*)(ws + o_zh);
  float* bias = (float*)(ws + o_b);
  float* WxT  = (float*)(ws + o_wxt);
  __hip_bfloat16* whb = (__hip_bfloat16*)(ws + o_whb);
  float* cbuf = (float*)(ws + o_c);
  __hip_bfloat16* hm0 = (__hip_bfloat16*)(ws + o_h0);
  __hip_bfloat16* hm1 = (__hip_bfloat16*)(ws + o_h1);
  __hip_bfloat16* xpb = (__hip_bfloat16*)(ws + o_xp);

  float* out_hn = (float*)d_out;
  float* out_ht = out_hn + (size_t)TT*BB*HH;   // h_t then c_t right after

  setup_kernel<<<5640, 256, 0, stream>>>(ux, uh, p_logit, bx, bh, Wh,
                                         zx, zh, bias, whb);
  transpose_wx<<<dim3(8,16,4), dim3(32,8), 0, stream>>>(Wx, WxT);
  xproj_gemm<<<8192, 256, 0, stream>>>(input, zx, WxT, xpb);

  for (int t = 0; t < TT; t++){
    const u32* hp = (t & 1) ? (const u32*)hm0 : (const u32*)hm1; // reads buf (t-1)&1
    __hip_bfloat16* hw = (t & 1) ? hm1 : hm0;                     // writes buf t&1
    lstm_step<<<256, 256, 0, stream>>>(xpb, (const u32*)whb, zh, bias,
                                       hp, hw, cbuf, out_hn, out_ht, t);
  }
}